// Round 5
// baseline (153.841 us; speedup 1.0000x reference)
//
#include <hip/hip_runtime.h>
#include <hip/hip_bf16.h>

#define D_MODEL 1024
#define N_HEADS 16
#define DH      64
#define BATCH   2
#define SEQ     2048
#define M_ROWS  (BATCH*SEQ)   // 4096

using f32x4  = __attribute__((ext_vector_type(4)))  float;
using f32x16 = __attribute__((ext_vector_type(16))) float;
using bfx8   = __attribute__((ext_vector_type(8)))  short;   // 8 bf16 in 4 VGPRs

__device__ __forceinline__ float bf2f(unsigned short u){
    unsigned int v = ((unsigned int)u) << 16;
    float f; __builtin_memcpy(&f, &v, 4); return f;
}
__device__ __forceinline__ unsigned short f2bf(float f){
    unsigned int u; __builtin_memcpy(&u, &f, 4);
    u = (u + 0x7FFFu + ((u >> 16) & 1u)) >> 16;   // RNE
    return (unsigned short)u;
}
__device__ __forceinline__ unsigned int cvtpk_bf16(float lo, float hi){
    unsigned int r;
    asm("v_cvt_pk_bf16_f32 %0, %1, %2" : "=v"(r) : "v"(lo), "v"(hi));
    return r;
}

typedef __attribute__((address_space(3))) void as3_void;
typedef __attribute__((address_space(1))) const void as1_cvoid;
__device__ __forceinline__ void gload16(const void* g, void* l){
    __builtin_amdgcn_global_load_lds((as1_cvoid*)g, (as3_void*)l, 16, 0, 0);
}

// ---------------- cast x (f32 -> bf16), 4 elems/thread ----------------
__global__ void cast_x_kernel(const float* __restrict__ x, unsigned short* __restrict__ xb){
    int i = blockIdx.x*blockDim.x + threadIdx.x;
    float4 v = reinterpret_cast<const float4*>(x)[i];
    ushort4 o; o.x=f2bf(v.x); o.y=f2bf(v.y); o.z=f2bf(v.z); o.w=f2bf(v.w);
    reinterpret_cast<ushort4*>(xb)[i] = o;
}

// ---------- cast+transpose weights: w[k][n] f32 -> wt[n][k] bf16 ----------
__global__ void transpose_cast_w(const float* __restrict__ w0, const float* __restrict__ w1,
                                 const float* __restrict__ w2, const float* __restrict__ w3,
                                 unsigned short* __restrict__ o0, unsigned short* __restrict__ o1,
                                 unsigned short* __restrict__ o2, unsigned short* __restrict__ o3){
    __shared__ float tile[32][33];
    const float* w; unsigned short* o;
    switch (blockIdx.z){
        case 0:  w=w0; o=o0; break;
        case 1:  w=w1; o=o1; break;
        case 2:  w=w2; o=o2; break;
        default: w=w3; o=o3; break;
    }
    const int tx = threadIdx.x, ty = threadIdx.y;
    const int x0 = blockIdx.x*32, y0 = blockIdx.y*32;
    #pragma unroll
    for (int j=0;j<32;j+=8) tile[ty+j][tx] = w[(size_t)(y0+ty+j)*D_MODEL + x0 + tx];
    __syncthreads();
    #pragma unroll
    for (int j=0;j<32;j+=8) o[(size_t)(x0+ty+j)*D_MODEL + y0 + tx] = f2bf(tile[tx][ty+j]);
}

// ---------------- RoPE in place on Q,K (bf16), 8 elems = 4 pairs / thread ----------------
__global__ void rope_kernel(unsigned short* __restrict__ q, unsigned short* __restrict__ k){
    const int id = blockIdx.x*blockDim.x + threadIdx.x;
    const int half = BATCH*SEQ*(D_MODEL/8);          // 524288 groups per tensor
    unsigned short* p = (id < half) ? q : k;
    const int i  = (id < half) ? id : id - half;
    const int gd = i & (D_MODEL/8 - 1);              // 8-elem group within row
    const int bt = i >> 7;                           // 0..4095
    const int t  = bt & (SEQ-1);
    unsigned short* base = p + (size_t)bt*D_MODEL + gd*8;
    uint4 raw = *reinterpret_cast<uint4*>(base);
    unsigned short e[8]; __builtin_memcpy(e, &raw, 16);
    const float cfac = -0.02595256269f;              // -log2(10000)/512
    #pragma unroll
    for (int u=0; u<4; ++u){
        int pi = gd*4 + u;                           // pair index in [0,512)
        float invf = exp2f(cfac * (float)pi);
        float ang  = (float)t * invf;
        float s, c; sincosf(ang, &s, &c);
        float a = bf2f(e[2*u]), b = bf2f(e[2*u+1]);
        e[2*u]   = f2bf(a*c - b*s);
        e[2*u+1] = f2bf(b*c + a*s);
    }
    __builtin_memcpy(&raw, e, 16);
    *reinterpret_cast<uint4*>(base) = raw;
}

// ======== merged QKV GEMM: 3x C[4096][1024] = A * Wt^T, one launch =========
// blockIdx.x in [0,24): sel = x>>3 picks {Q,K,V}; V written transposed (B,H,DH,SEQ).
__global__ __launch_bounds__(256) void gemm_qkv(const unsigned short* __restrict__ A,
                                                const unsigned short* __restrict__ Bq,
                                                const unsigned short* __restrict__ Bk,
                                                const unsigned short* __restrict__ Bv,
                                                unsigned short* __restrict__ Qo,
                                                unsigned short* __restrict__ Ko,
                                                unsigned short* __restrict__ Vto){
    __shared__ unsigned short As[128*32];
    __shared__ unsigned short Bs[128*32];
    const int sel = blockIdx.x >> 3;
    const int n0  = (blockIdx.x & 7) * 128;
    const unsigned short* Bt = (sel==0) ? Bq : ((sel==1) ? Bk : Bv);
    const int tid = threadIdx.x;
    const int lane = tid & 63, wid = tid >> 6;
    const int l15 = lane & 15, hi = lane >> 4;
    const int wr = wid >> 1, wc = wid & 1;
    const int m0 = blockIdx.y * 128;

    f32x4 acc[4][4] = {};

    for (int kt = 0; kt < D_MODEL; kt += 32){
        __syncthreads();
        #pragma unroll
        for (int i = 0; i < 2; ++i){
            int c = tid + 256*i;
            const unsigned short* ga = A  + (size_t)(m0 + (c>>2))*D_MODEL + kt + (c&3)*8;
            gload16(ga, As + c*8);
            const unsigned short* gb = Bt + (size_t)(n0 + (c>>2))*D_MODEL + kt + (c&3)*8;
            gload16(gb, Bs + c*8);
        }
        asm volatile("s_waitcnt vmcnt(0)" ::: "memory");
        __syncthreads();
        bfx8 a[4], b[4];
        #pragma unroll
        for (int t = 0; t < 4; ++t){
            a[t] = *reinterpret_cast<const bfx8*>(As + (64*wr + 16*t + l15)*32 + 8*hi);
            b[t] = *reinterpret_cast<const bfx8*>(Bs + (64*wc + 16*t + l15)*32 + 8*hi);
        }
        #pragma unroll
        for (int rt = 0; rt < 4; ++rt)
            #pragma unroll
            for (int ct = 0; ct < 4; ++ct)
                acc[rt][ct] = __builtin_amdgcn_mfma_f32_16x16x32_bf16(a[rt], b[ct], acc[rt][ct], 0, 0, 0);
    }

    #pragma unroll
    for (int rt = 0; rt < 4; ++rt)
        #pragma unroll
        for (int ct = 0; ct < 4; ++ct){
            const int m = m0 + 64*wr + 16*rt + 4*hi;
            const int n = n0 + 64*wc + 16*ct + l15;
            if (sel < 2){
                unsigned short* o = sel ? Ko : Qo;
                #pragma unroll
                for (int r=0;r<4;++r) o[(size_t)(m+r)*D_MODEL + n] = f2bf(acc[rt][ct][r]);
            } else {
                const int b  = m >> 11, t = m & (SEQ-1);
                const int h  = n >> 6,  d = n & 63;
                ushort4 pk;
                pk.x = f2bf(acc[rt][ct][0]); pk.y = f2bf(acc[rt][ct][1]);
                pk.z = f2bf(acc[rt][ct][2]); pk.w = f2bf(acc[rt][ct][3]);
                *reinterpret_cast<ushort4*>(Vto + ((size_t)((b*N_HEADS + h)*DH + d))*SEQ + t) = pk;
            }
        }
}

// ---------------- final GEMM: f32 out ----------------
__global__ __launch_bounds__(256) void gemm_out(const unsigned short* __restrict__ A,
                                                const unsigned short* __restrict__ Bt,
                                                float* __restrict__ dst){
    __shared__ unsigned short As[128*32];
    __shared__ unsigned short Bs[128*32];
    const int tid = threadIdx.x;
    const int lane = tid & 63, wid = tid >> 6;
    const int l15 = lane & 15, hi = lane >> 4;
    const int wr = wid >> 1, wc = wid & 1;
    const int m0 = blockIdx.y * 128, n0 = blockIdx.x * 128;

    f32x4 acc[4][4] = {};

    for (int kt = 0; kt < D_MODEL; kt += 32){
        __syncthreads();
        #pragma unroll
        for (int i = 0; i < 2; ++i){
            int c = tid + 256*i;
            const unsigned short* ga = A  + (size_t)(m0 + (c>>2))*D_MODEL + kt + (c&3)*8;
            gload16(ga, As + c*8);
            const unsigned short* gb = Bt + (size_t)(n0 + (c>>2))*D_MODEL + kt + (c&3)*8;
            gload16(gb, Bs + c*8);
        }
        asm volatile("s_waitcnt vmcnt(0)" ::: "memory");
        __syncthreads();
        bfx8 a[4], b[4];
        #pragma unroll
        for (int t = 0; t < 4; ++t){
            a[t] = *reinterpret_cast<const bfx8*>(As + (64*wr + 16*t + l15)*32 + 8*hi);
            b[t] = *reinterpret_cast<const bfx8*>(Bs + (64*wc + 16*t + l15)*32 + 8*hi);
        }
        #pragma unroll
        for (int rt = 0; rt < 4; ++rt)
            #pragma unroll
            for (int ct = 0; ct < 4; ++ct)
                acc[rt][ct] = __builtin_amdgcn_mfma_f32_16x16x32_bf16(a[rt], b[ct], acc[rt][ct], 0, 0, 0);
    }

    #pragma unroll
    for (int rt = 0; rt < 4; ++rt)
        #pragma unroll
        for (int ct = 0; ct < 4; ++ct){
            const int m = m0 + 64*wr + 16*rt + 4*hi;
            const int n = n0 + 64*wc + 16*ct + l15;
            #pragma unroll
            for (int r=0;r<4;++r) dst[(size_t)(m+r)*D_MODEL + n] = acc[rt][ct][r];
        }
}

// ======================= causal flash attention v4 ==========================
// 2048 one-wave blocks (64 thr). Block = (b,h, 32 q-rows). No LDS, no barriers:
// K/V read directly from global (L2-resident; heads XCD-grouped via bid&7).
// Swapped 32x32 QK^T -> P in registers; 32-k subtiles (diagonal = last step);
// in-register softmax (exp2 fused scale), defer-max, cvt_pk+shfl_xor(32) pack.
// K prefetched one subtile ahead. Longest-qt-first for drain balance.
// ===========================================================================
__global__ __launch_bounds__(64, 2) void attn_kernel(const unsigned short* __restrict__ Q,
                                                     const unsigned short* __restrict__ K,
                                                     const unsigned short* __restrict__ Vt,
                                                     unsigned short* __restrict__ O){
    const int lane = threadIdx.x;
    const int l31 = lane & 31, hi2 = lane >> 5;
    const int bid = blockIdx.x;
    const int xcd = bid & 7, j = bid >> 3;
    const int hp  = xcd*4 + (j & 3);            // (b,h) index 0..31, 4 heads per XCD
    const int b = hp >> 4, h = hp & 15;
    const int qt = 63 - (j >> 2);               // longest first
    const int qrow = qt*32 + l31;               // this lane's q row

    const unsigned short* Kbase = K  + (size_t)(b*SEQ)*D_MODEL + h*DH + 8*hi2;
    const unsigned short* Vbase = Vt + ((size_t)((b*N_HEADS + h)*DH))*SEQ + 8*hi2;

    // Q fragments (B-operand): qf[m] = Q[qrow][16m + 8*hi2 .. +8]
    bfx8 qf[4];
    {
        const unsigned short* qp = Q + ((size_t)(b*SEQ) + qrow)*D_MODEL + h*DH + 8*hi2;
        #pragma unroll
        for (int m=0;m<4;++m) qf[m] = *reinterpret_cast<const bfx8*>(qp + 16*m);
    }

    f32x16 oacc[2] = {};
    float m_r = -1e30f, l_r = 0.f;
    const float k2 = 0.18033688011f;            // 0.125 * log2(e)

    // prologue: K fragments for subtile 0 (A-operand: lane = k-row)
    bfx8 kf[4];
    #pragma unroll
    for (int m=0;m<4;++m) kf[m] = *reinterpret_cast<const bfx8*>(Kbase + (size_t)l31*D_MODEL + 16*m);

    for (int sk = 0; sk <= qt; ++sk){
        // V fragments for this subtile (B-operand: lane = dh), issued early
        bfx8 vf[2][2];
        #pragma unroll
        for (int dt=0; dt<2; ++dt)
            #pragma unroll
            for (int ks=0; ks<2; ++ks)
                vf[dt][ks] = *reinterpret_cast<const bfx8*>(Vbase + (size_t)(32*dt + l31)*SEQ + sk*32 + 16*ks);

        // ---- S^T = K Q^T (32x32, dh=64) ----
        f32x16 st = {};
        __builtin_amdgcn_s_setprio(1);
        #pragma unroll
        for (int m=0; m<4; ++m)
            st = __builtin_amdgcn_mfma_f32_32x32x16_bf16(kf[m], qf[m], st, 0,0,0);
        __builtin_amdgcn_s_setprio(0);

        // ---- prefetch next K subtile (hidden under softmax+PV) ----
        bfx8 kn[4];
        if (sk < qt){
            const unsigned short* kp = Kbase + (size_t)(sk+1)*32*D_MODEL + (size_t)l31*D_MODEL;
            #pragma unroll
            for (int m=0;m<4;++m) kn[m] = *reinterpret_cast<const bfx8*>(kp + 16*m);
        }

        // ---- causal mask (diagonal subtile = last step only) + row max ----
        float p[16]; float pm = -3e38f;
        if (sk == qt){
            #pragma unroll
            for (int r=0;r<16;++r){
                int kg = sk*32 + (r&3) + 8*(r>>2) + 4*hi2;
                float v = (kg > qrow) ? -1e30f : st[r];
                p[r] = v; pm = fmaxf(pm, v);
            }
        } else {
            #pragma unroll
            for (int r=0;r<16;++r){ p[r] = st[r]; pm = fmaxf(pm, st[r]); }
        }
        pm = fmaxf(pm, __shfl_xor(pm, 32));

        // ---- deferred rescale (raw-logit THR=64 ≈ 8 ln-units) ----
        if (__any(pm - m_r > 64.f)){
            float mnew  = fmaxf(m_r, pm);
            float alpha = exp2f((m_r - mnew)*k2);
            m_r = mnew; l_r *= alpha;
            #pragma unroll
            for (int r=0;r<16;++r){
                float ac = __shfl(alpha, (r&3) + 8*(r>>2) + 4*hi2);
                oacc[0][r] *= ac; oacc[1][r] *= ac;
            }
        }

        // ---- exp (fused scale via exp2) + row sum ----
        const float mk = m_r * k2;
        float rs = 0.f;
        #pragma unroll
        for (int r=0;r<16;++r){
            float e = exp2f(__builtin_fmaf(p[r], k2, -mk));
            p[r] = e; rs += e;
        }
        rs += __shfl_xor(rs, 32);
        l_r += rs;

        // ---- pack P -> PV A-fragments (cvt_pk + cross-half shfl) ----
        unsigned int c[8], x[8];
        #pragma unroll
        for (int q=0;q<8;++q) c[q] = cvtpk_bf16(p[2*q], p[2*q+1]);
        #pragma unroll
        for (int q=0;q<8;++q) x[q] = __shfl_xor(c[q], 32);
        uint4 w0 = (hi2==0) ? make_uint4(c[0],c[1],x[0],x[1]) : make_uint4(x[2],x[3],c[2],c[3]);
        uint4 w1 = (hi2==0) ? make_uint4(c[4],c[5],x[4],x[5]) : make_uint4(x[6],x[7],c[6],c[7]);
        bfx8 pa0 = *reinterpret_cast<bfx8*>(&w0);
        bfx8 pa1 = *reinterpret_cast<bfx8*>(&w1);

        // ---- O += P V ----
        __builtin_amdgcn_s_setprio(1);
        #pragma unroll
        for (int dt=0; dt<2; ++dt){
            f32x16 o = oacc[dt];
            o = __builtin_amdgcn_mfma_f32_32x32x16_bf16(pa0, vf[dt][0], o, 0,0,0);
            o = __builtin_amdgcn_mfma_f32_32x32x16_bf16(pa1, vf[dt][1], o, 0,0,0);
            oacc[dt] = o;
        }
        __builtin_amdgcn_s_setprio(0);

        if (sk < qt){
            #pragma unroll
            for (int m=0;m<4;++m) kf[m] = kn[m];
        }
    }

    // ---- epilogue: normalize and store ----
    float inv = 1.0f / l_r;
    #pragma unroll
    for (int r=0; r<16; ++r){
        const int crow = (r&3) + 8*(r>>2) + 4*hi2;
        float ic = __shfl(inv, crow);
        const int row = qt*32 + crow;
        #pragma unroll
        for (int dt=0; dt<2; ++dt)
            O[((size_t)(b*SEQ) + row)*D_MODEL + h*DH + 32*dt + l31] = f2bf(oacc[dt][r] * ic);
    }
}

extern "C" void kernel_launch(void* const* d_in, const int* in_sizes, int n_in,
                              void* d_out, int out_size, void* d_ws, size_t ws_size,
                              hipStream_t stream) {
    const float* x  = (const float*)d_in[0];
    // d_in[1] = causal mask (bool) — deterministic tril, unused
    const float* wq = (const float*)d_in[2];
    const float* wk = (const float*)d_in[3];
    const float* wv = (const float*)d_in[4];
    const float* wo = (const float*)d_in[5];

    char* ws = (char*)d_ws;
    unsigned short* xb  = (unsigned short*)(ws);                     // 8 MB
    unsigned short* wqt = (unsigned short*)(ws + (8u  << 20));       // 2 MB each
    unsigned short* wkt = (unsigned short*)(ws + (10u << 20));
    unsigned short* wvt = (unsigned short*)(ws + (12u << 20));
    unsigned short* wot = (unsigned short*)(ws + (14u << 20));
    unsigned short* Qb  = (unsigned short*)(ws + (16u << 20));       // 8 MB
    unsigned short* Kb  = (unsigned short*)(ws + (24u << 20));       // 8 MB
    unsigned short* Vt  = (unsigned short*)(ws + (32u << 20));       // 8 MB (B,H,DH,SEQ)
    unsigned short* Ob  = (unsigned short*)(ws + (40u << 20));       // 8 MB

    cast_x_kernel<<<M_ROWS*D_MODEL/4/256, 256, 0, stream>>>(x, xb);
    transpose_cast_w<<<dim3(32,32,4), dim3(32,8), 0, stream>>>(wq,wk,wv,wo, wqt,wkt,wvt,wot);

    gemm_qkv<<<dim3(24,32), 256, 0, stream>>>(xb, wqt, wkt, wvt, Qb, Kb, Vt);

    rope_kernel<<<2*M_ROWS*(D_MODEL/8)/256, 256, 0, stream>>>(Qb, Kb);

    attn_kernel<<<2048, 64, 0, stream>>>(Qb, Kb, Vt, Ob);

    gemm_out<<<dim3(8,32), 256, 0, stream>>>(Ob, wot, (float*)d_out);
}